// Round 1
// baseline (1009.136 us; speedup 1.0000x reference)
//
#include <hip/hip_runtime.h>
#include <cstdint>
#include <cstddef>

// ---------------------------------------------------------------------------
// GATAttention: B=8, M=50000, d=256, heads=8, head_dim=32, gsl_hidden=16, k=500
//
// Decomposition:
//   U[b,h,:]  = sum_m exp(A_mod[b,m,h]) * h[b,m,:]
//             = sumh[b,:] + sum_{masked m} (exp(A[b,m,h])-1) * h[b,m,:]
//   Z[b,h]    = (M - cnt_masked) + sum_{masked} exp(A[b,m,h])
//   out[b,e]  = relu( (U[b,e>>5,:]@w_w[:,e])/Z + relu(mean_h@res_w[:,e]+res_b) )
//   then normalize over e.  mask from f64-exact gate logit z (sigmoid monotone).
// ---------------------------------------------------------------------------

#define MM     50000
#define BATCH  8
#define TILES  196            // ceil(50000/256)

// workspace layout (bytes)
#define OFF_A        0u               // float  [B*M*8]   12,800,000
#define OFF_KHI      12800000u        // u32    [B*M]      1,600,000
#define OFF_KLO      14400000u        // u32    [B*M]      1,600,000
#define OFF_G64      16000000u        // double [256*16]      32,768
#define OFF_G2W      16032768u        // double [16]             128
#define OFF_G2B      16032896u        // double [1]                8
#define OFF_SUMH     16032904u        // float  [8*256]        8,192   (zeroed)
#define OFF_UCORR    (OFF_SUMH + 8192u)      // float [8*8*256] 65,536 (zeroed)
#define OFF_ZCORR    (OFF_SUMH + 73728u)     // float [8*8]        256 (zeroed)
#define OFF_CCNT     (OFF_SUMH + 73984u)     // int   [8]           32 (zeroed)
#define ZERO_SZ      74016u
#define OFF_KTHHI    16106920u        // u32 [8]
#define OFF_KTHLO    16106952u        // u32 [8]
#define OFF_COMPACT  16106984u        // int [8*4096]        131,072
// total ~16.24 MB

// ---------------------------------------------------------------------------
// k0: promote gsl weights to f64 once per call
__global__ __launch_bounds__(256) void k0_conv(
    const float* __restrict__ g1w, const float* __restrict__ g2w,
    const float* __restrict__ g2b,
    double* __restrict__ g64, double* __restrict__ g2w64, double* __restrict__ g2b64)
{
    int t = threadIdx.x;
    for (int i = t; i < 4096; i += 256) g64[i] = (double)g1w[i];
    if (t < 16) g2w64[t] = (double)g2w[t];
    if (t == 0) g2b64[0] = (double)g2b[0];
}

// ---------------------------------------------------------------------------
// k1: single streaming pass over h.
//  - per row: A[8] (f32), gate logit z (f64), store sortable key (hi32/lo32)
//  - column sums of h into sumh[b][256]
// 256 threads = 4 waves; each wave owns 64 rows; per-wave private LDS
// double buffer, transposed [k][row] layout, no __syncthreads in K-loop.
__global__ __launch_bounds__(256) void k1_main(
    const float* __restrict__ h,
    const float* __restrict__ att_w,   // [256][8]
    const float* __restrict__ att_b,   // [8]
    const float* __restrict__ g1b,     // [16]
    const double* __restrict__ g64,    // [256][16]
    const double* __restrict__ g2w64,  // [16]
    const double* __restrict__ g2b64,  // [1]
    float* __restrict__ Aout,          // [B*M][8]
    unsigned int* __restrict__ khi,
    unsigned int* __restrict__ klo,
    float* __restrict__ sumh)          // [B][256]
{
    __shared__ float tile[4][2][16][65];   // [wave][buf][k][row(+pad)]
    __shared__ float lsum[256];

    const int tid  = threadIdx.x;
    const int w    = tid >> 6;
    const int lane = tid & 63;
    lsum[tid] = 0.0f;
    __syncthreads();

    const int bid = blockIdx.x;
    const int b   = bid / TILES;
    const int t0  = bid % TILES;
    const int wave_row0 = t0 * 256 + w * 64;
    const size_t batch_base = (size_t)b * MM;

    const int kq   = lane & 3;    // which 4-float quad in the 16-k chunk
    const int rsub = lane >> 2;   // row sub-index for loads

    float  aacc[8];
    double gacc[16];
#pragma unroll
    for (int j = 0; j < 8; ++j) aacc[j] = 0.0f;
#pragma unroll
    for (int g = 0; g < 16; ++g) gacc[g] = 0.0;

    // stage chunk 0 -> buffer 0
    {
        float4 v[4];
#pragma unroll
        for (int i = 0; i < 4; ++i) {
            int row_w = i * 16 + rsub;
            int m  = wave_row0 + row_w;
            int mc = (m < MM) ? m : (MM - 1);
            const float4* p = (const float4*)(h + (batch_base + (size_t)mc) * 256 + kq * 4);
            float4 t = *p;
            if (m >= MM) { t.x = 0.f; t.y = 0.f; t.z = 0.f; t.w = 0.f; }
            v[i] = t;
        }
#pragma unroll
        for (int i = 0; i < 4; ++i) {
            int row_w = i * 16 + rsub;
            tile[w][0][kq*4+0][row_w] = v[i].x;
            tile[w][0][kq*4+1][row_w] = v[i].y;
            tile[w][0][kq*4+2][row_w] = v[i].z;
            tile[w][0][kq*4+3][row_w] = v[i].w;
        }
    }

    int cb = 0;
    for (int c = 0; c < 16; ++c) {
        float4 nv[4];
        const bool has = (c < 15);
        if (has) {
#pragma unroll
            for (int i = 0; i < 4; ++i) {
                int row_w = i * 16 + rsub;
                int m  = wave_row0 + row_w;
                int mc = (m < MM) ? m : (MM - 1);
                const float4* p = (const float4*)(h + (batch_base + (size_t)mc) * 256
                                                  + (c + 1) * 16 + kq * 4);
                float4 t = *p;
                if (m >= MM) { t.x = 0.f; t.y = 0.f; t.z = 0.f; t.w = 0.f; }
                nv[i] = t;
            }
        }
        const int k0 = c * 16;
#pragma unroll
        for (int kk = 0; kk < 16; ++kk) {
            float  hv = tile[w][cb][kk][lane];
            double hd = (double)hv;
            const float* aw = att_w + (k0 + kk) * 8;      // wave-uniform -> s_load
#pragma unroll
            for (int j = 0; j < 8; ++j) aacc[j] = fmaf(hv, aw[j], aacc[j]);
            const double* gw = g64 + (k0 + kk) * 16;      // wave-uniform -> s_load
#pragma unroll
            for (int g = 0; g < 16; ++g) gacc[g] = fma(hd, gw[g], gacc[g]);
        }
        // column sums of this chunk (rides the staged tile)
        {
            const int dsub = lane & 15;
            const int rq   = lane >> 4;
            float s = 0.f;
#pragma unroll
            for (int i = 0; i < 16; ++i) s += tile[w][cb][dsub][rq * 16 + i];
            s += __shfl_xor(s, 16, 64);
            s += __shfl_xor(s, 32, 64);
            if (lane < 16) atomicAdd(&lsum[k0 + lane], s);
        }
        if (has) {
            const int nb = cb ^ 1;
#pragma unroll
            for (int i = 0; i < 4; ++i) {
                int row_w = i * 16 + rsub;
                tile[w][nb][kq*4+0][row_w] = nv[i].x;
                tile[w][nb][kq*4+1][row_w] = nv[i].y;
                tile[w][nb][kq*4+2][row_w] = nv[i].z;
                tile[w][nb][kq*4+3][row_w] = nv[i].w;
            }
            cb = nb;
        }
    }

    // epilogue
    const int m = wave_row0 + lane;
    if (m < MM) {
        size_t row = batch_base + (size_t)m;
        float4 A0, A1;
        A0.x = fmaxf(aacc[0] + att_b[0], 0.f);
        A0.y = fmaxf(aacc[1] + att_b[1], 0.f);
        A0.z = fmaxf(aacc[2] + att_b[2], 0.f);
        A0.w = fmaxf(aacc[3] + att_b[3], 0.f);
        A1.x = fmaxf(aacc[4] + att_b[4], 0.f);
        A1.y = fmaxf(aacc[5] + att_b[5], 0.f);
        A1.z = fmaxf(aacc[6] + att_b[6], 0.f);
        A1.w = fmaxf(aacc[7] + att_b[7], 0.f);
        float4* Ap = (float4*)(Aout + row * 8);
        Ap[0] = A0; Ap[1] = A1;

        double z = g2b64[0];
#pragma unroll
        for (int g = 0; g < 16; ++g) {
            double sg = gacc[g] + (double)g1b[g];
            sg = sg > 0.0 ? sg : 0.0;
            z = fma(sg, g2w64[g], z);
        }
        long long uz = __double_as_longlong(z);
        unsigned long long key = (uz < 0)
            ? ~((unsigned long long)uz)
            : ((unsigned long long)uz | 0x8000000000000000ULL);
        khi[row] = (unsigned int)(key >> 32);
        klo[row] = (unsigned int)(key & 0xffffffffULL);
    }
    __syncthreads();
    atomicAdd(&sumh[b * 256 + tid], lsum[tid]);
}

// ---------------------------------------------------------------------------
// k2: exact 64-bit radix select of the k-th largest key per batch.
// 4x 8-bit passes on hi32, then exact bitwise select on lo32 of the
// hi-equal candidate set.
__global__ __launch_bounds__(1024) void k2_select(
    const unsigned int* __restrict__ khi,
    const unsigned int* __restrict__ klo,
    const int* __restrict__ kptr,
    unsigned int* __restrict__ kth_hi,
    unsigned int* __restrict__ kth_lo)
{
    __shared__ int hist[256];
    __shared__ unsigned int s_pref;
    __shared__ int s_kk;
    __shared__ unsigned int s_cand[2048];
    __shared__ int s_ncand;
    __shared__ int s_cnt;

    const int b   = blockIdx.x;
    const int tid = threadIdx.x;
    const size_t base = (size_t)b * MM;

    if (tid == 0) {
        int k = *kptr;
        s_pref = 0u;
        s_kk = (k < MM) ? k : MM;
        s_ncand = 0;
    }
    __syncthreads();

    for (int p = 0; p < 4; ++p) {
        if (tid < 256) hist[tid] = 0;
        __syncthreads();
        const int shift = 24 - 8 * p;
        const unsigned int pref = s_pref;
        for (int m = tid; m < MM; m += 1024) {
            unsigned int key = khi[base + m];
            if (((key >> shift) >> 8) == pref)
                atomicAdd(&hist[(key >> shift) & 255u], 1);
        }
        __syncthreads();
        if (tid == 0) {
            int kk = s_kk, cum = 0;
            for (int d = 255; d >= 0; --d) {
                cum += hist[d];
                if (cum >= kk) {
                    s_kk = kk - (cum - hist[d]);
                    s_pref = (pref << 8) | (unsigned int)d;
                    break;
                }
            }
        }
        __syncthreads();
    }
    const unsigned int hsel = s_pref;
    const int rr = s_kk;     // 1-based rank within hi-equal group

    for (int m = tid; m < MM; m += 1024) {
        if (khi[base + m] == hsel) {
            int pos = atomicAdd(&s_ncand, 1);
            if (pos < 2048) s_cand[pos] = klo[base + m];
        }
    }
    __syncthreads();
    int n = s_ncand; if (n > 2048) n = 2048;

    unsigned int p_lo = 0;
    int kk = rr;
    for (int bit = 31; bit >= 0; --bit) {
        if (tid == 0) s_cnt = 0;
        __syncthreads();
        unsigned int hi_mask = (bit == 31) ? 0u : (0xFFFFFFFFu << (bit + 1));
        int loc = 0;
        for (int i = tid; i < n; i += 1024) {
            unsigned int x = s_cand[i];
            if (((x & hi_mask) == (p_lo & hi_mask)) && (x & (1u << bit))) loc++;
        }
        if (loc) atomicAdd(&s_cnt, loc);
        __syncthreads();
        int c1 = s_cnt;
        if (c1 >= kk) p_lo |= (1u << bit);
        else kk -= c1;
        __syncthreads();
    }
    if (tid == 0) { kth_hi[b] = hsel; kth_lo[b] = p_lo; }
}

// ---------------------------------------------------------------------------
// k3: mask output + compaction of masked indices + Zcorr
__global__ __launch_bounds__(256) void k3_mask(
    const unsigned int* __restrict__ khi,
    const unsigned int* __restrict__ klo,
    const unsigned int* __restrict__ kth_hi,
    const unsigned int* __restrict__ kth_lo,
    const float* __restrict__ A,
    float* __restrict__ maskout,
    int* __restrict__ ccount,
    int* __restrict__ compact,
    float* __restrict__ Zcorr)
{
    int bid = blockIdx.x;
    int b = bid / TILES, t0 = bid % TILES;
    int m = t0 * 256 + threadIdx.x;
    if (m >= MM) return;
    size_t row = (size_t)b * MM + m;
    unsigned int hi  = khi[row];
    unsigned int thi = kth_hi[b];
    bool mk;
    if (hi > thi)      mk = true;
    else if (hi < thi) mk = false;
    else               mk = (klo[row] >= kth_lo[b]);
    maskout[row] = mk ? 1.0f : 0.0f;
    if (mk) {
        int pos = atomicAdd(&ccount[b], 1);
        if (pos < 4096) compact[b * 4096 + pos] = m;
        const float* Ap = A + row * 8;
#pragma unroll
        for (int j = 0; j < 8; ++j)
            atomicAdd(&Zcorr[b * 8 + j], expf(Ap[j]) - 1.0f);
    }
}

// ---------------------------------------------------------------------------
// k4: sparse correction U_corr[b][h][d] = sum_{masked} (exp(A)-1) * h
// 32 blocks per batch over the compacted list; thread = d.
__global__ __launch_bounds__(256) void k4_corr(
    const float* __restrict__ h,
    const float* __restrict__ A,
    const int* __restrict__ compact,
    const int* __restrict__ ccount,
    float* __restrict__ Ucorr)
{
    int b    = blockIdx.x >> 5;
    int part = blockIdx.x & 31;
    int tid  = threadIdx.x;
    int n = ccount[b]; if (n > 4096) n = 4096;
    float acc[8];
#pragma unroll
    for (int j = 0; j < 8; ++j) acc[j] = 0.f;
    for (int i = part; i < n; i += 32) {
        int m = compact[b * 4096 + i];
        size_t row = (size_t)b * MM + m;
        const float* Ap = A + row * 8;       // uniform per block -> s_load
        float hv = h[row * 256 + tid];
#pragma unroll
        for (int j = 0; j < 8; ++j)
            acc[j] = fmaf(expf(Ap[j]) - 1.0f, hv, acc[j]);
    }
#pragma unroll
    for (int j = 0; j < 8; ++j)
        atomicAdd(&Ucorr[(b * 8 + j) * 256 + tid], acc[j]);
}

// ---------------------------------------------------------------------------
// k5: epilogue. attn projection, Q_res, relu, layernorm-style normalize.
__global__ __launch_bounds__(256) void k5_final(
    const float* __restrict__ sumh,
    const float* __restrict__ Ucorr,
    const float* __restrict__ Zcorr,
    const int* __restrict__ ccount,
    const float* __restrict__ w_w,     // [256][256]
    const float* __restrict__ res_w,   // [256][256]
    const float* __restrict__ res_b,   // [256]
    float* __restrict__ out0)
{
    __shared__ float Us[8 * 256];
    __shared__ float ms[256];
    __shared__ float red[256];
    __shared__ float s_mean, s_var;

    int b = blockIdx.x, e = threadIdx.x;
    float sh = sumh[b * 256 + e];
    ms[e] = sh;
#pragma unroll
    for (int j = 0; j < 8; ++j)
        Us[j * 256 + e] = sh + Ucorr[(b * 8 + j) * 256 + e];
    __syncthreads();

    int hh = e >> 5;
    float Z = (float)(MM - ccount[b]) + Zcorr[b * 8 + hh];
    float attn = 0.f, qr = 0.f;
    for (int d = 0; d < 256; ++d) {
        attn = fmaf(Us[hh * 256 + d], w_w[d * 256 + e], attn);
        qr   = fmaf(ms[d],            res_w[d * 256 + e], qr);
    }
    float qres = fmaxf(qr * (1.0f / (float)MM) + res_b[e], 0.f);
    float pre  = fmaxf(attn / Z + qres, 0.f);

    red[e] = pre; __syncthreads();
    for (int s = 128; s > 0; s >>= 1) { if (e < s) red[e] += red[e + s]; __syncthreads(); }
    if (e == 0) s_mean = red[0] * (1.0f / 256.0f);
    __syncthreads();
    float mean = s_mean;
    float dv = pre - mean;
    red[e] = dv * dv; __syncthreads();
    for (int s = 128; s > 0; s >>= 1) { if (e < s) red[e] += red[e + s]; __syncthreads(); }
    if (e == 0) s_var = red[0] * (1.0f / 256.0f);
    __syncthreads();
    out0[b * 256 + e] = dv / sqrtf(s_var + 1e-8f);
}

// ---------------------------------------------------------------------------
extern "C" void kernel_launch(void* const* d_in, const int* in_sizes, int n_in,
                              void* d_out, int out_size, void* d_ws, size_t ws_size,
                              hipStream_t stream) {
    const float* h     = (const float*)d_in[0];
    const float* att_w = (const float*)d_in[1];
    const float* att_b = (const float*)d_in[2];
    const float* w_w   = (const float*)d_in[3];
    const float* res_w = (const float*)d_in[4];
    const float* res_b = (const float*)d_in[5];
    const float* g1w   = (const float*)d_in[6];
    const float* g1b   = (const float*)d_in[7];
    const float* g2w   = (const float*)d_in[8];
    const float* g2b   = (const float*)d_in[9];
    const int*   kptr  = (const int*)d_in[10];

    char* ws = (char*)d_ws;
    float*        A       = (float*)(ws + OFF_A);
    unsigned int* khi     = (unsigned int*)(ws + OFF_KHI);
    unsigned int* klo     = (unsigned int*)(ws + OFF_KLO);
    double*       g64     = (double*)(ws + OFF_G64);
    double*       g2w64   = (double*)(ws + OFF_G2W);
    double*       g2b64   = (double*)(ws + OFF_G2B);
    float*        sumh    = (float*)(ws + OFF_SUMH);
    float*        Ucorr   = (float*)(ws + OFF_UCORR);
    float*        Zcorr   = (float*)(ws + OFF_ZCORR);
    int*          ccnt    = (int*)(ws + OFF_CCNT);
    unsigned int* kthhi   = (unsigned int*)(ws + OFF_KTHHI);
    unsigned int* kthlo   = (unsigned int*)(ws + OFF_KTHLO);
    int*          compact = (int*)(ws + OFF_COMPACT);

    float* out0    = (float*)d_out;
    float* maskout = out0 + BATCH * 256;   // output 1 starts after 8*1*256

    // zero the accumulator region (ws is poisoned before every call)
    hipMemsetAsync(ws + OFF_SUMH, 0, ZERO_SZ, stream);

    k0_conv  <<<1,            256,  0, stream>>>(g1w, g2w, g2b, g64, g2w64, g2b64);
    k1_main  <<<BATCH*TILES,  256,  0, stream>>>(h, att_w, att_b, g1b, g64, g2w64, g2b64,
                                                 A, khi, klo, sumh);
    k2_select<<<BATCH,        1024, 0, stream>>>(khi, klo, kptr, kthhi, kthlo);
    k3_mask  <<<BATCH*TILES,  256,  0, stream>>>(khi, klo, kthhi, kthlo, A,
                                                 maskout, ccnt, compact, Zcorr);
    k4_corr  <<<BATCH*32,     256,  0, stream>>>(h, A, compact, ccnt, Ucorr);
    k5_final <<<BATCH,        256,  0, stream>>>(sumh, Ucorr, Zcorr, ccnt,
                                                 w_w, res_w, res_b, out0);
}

// Round 2
// 937.136 us; speedup vs baseline: 1.0768x; 1.0768x over previous
//
#include <hip/hip_runtime.h>
#include <cstdint>
#include <cstddef>

// ---------------------------------------------------------------------------
// GATAttention: B=8, M=50000, d=256, heads=8, head_dim=32, gsl_hidden=16, k=500
//   U[b,h,:]  = sumh[b,:] + sum_{masked m} (exp(A[b,m,h])-1) * h[b,m,:]
//   Z[b,h]    = (M - cnt) + sum_{masked} exp(A[b,m,h])
//   out[b,e]  = normalize(relu( U[b,e>>5,:]@w_w[:,e]/Z + relu(mean_h@res_w+res_b) ))
//   mask from f64-exact gate logit (sigmoid monotone -> skipped).
// Round-2: weights in LDS (all-DS inner loop, no SMEM/DS lgkm mixing);
// sampling-based exact select (no 50k-wide atomic histograms); ballot-
// aggregated compaction; f64 accumulators.
// ---------------------------------------------------------------------------

#define MM     50000
#define BATCH  8
#define TILES  196            // ceil(50000/256)
#define CH     8              // k-chunk in k1
#define NCHUNK 32             // 256/CH

// workspace layout (bytes)
#define OFF_A        0u                    // float  [B*M*8]   12,800,000
#define OFF_KEYS     12800000u             // u64    [B*M]      3,200,000
#define OFF_SUMH     16000000u             // double [8*256]       16,384 (zeroed)
#define OFF_UCORR    16016384u             // double [8*8*256]    131,072 (zeroed)
#define OFF_ZCORR    16147456u             // double [8*8]            512 (zeroed)
#define OFF_CCNT     16147968u             // int    [8]               32 (zeroed)
#define ZERO_SZ      148000u
#define OFF_KTH      16148000u             // u64    [8]
#define OFF_COMPACT  16148064u             // int    [8*2048]      65,536
// end 16,213,600 (round-1 footprint 16,238,056 worked -> fits)

// ---------------------------------------------------------------------------
// k1: single streaming pass over h. Weights staged to LDS once per block so
// the inner loop is pure DS (in-order lgkm -> fine-grained waits).
// 4 waves/block, 64 rows/wave, per-wave private single-buffered 8-k tile.
__global__ __launch_bounds__(256) void k1_main(
    const float* __restrict__ h,
    const float* __restrict__ att_w,   // [256][8]
    const float* __restrict__ att_b,   // [8]
    const float* __restrict__ g1w,     // [256][16]
    const float* __restrict__ g1b,     // [16]
    const float* __restrict__ g2w,     // [16]
    const float* __restrict__ g2b,     // [1]
    float* __restrict__ Aout,          // [B*M][8]
    unsigned long long* __restrict__ keys,
    double* __restrict__ sumh)         // [B][256]
{
    __shared__ double gw_s[256][16];       // 32 KB
    __shared__ float  aw_s[256][8];        //  8 KB
    __shared__ float  tile[4][CH][65];     //  8.3 KB  [wave][k][row+pad]
    __shared__ float  lsum[256];

    const int tid  = threadIdx.x;
    const int w    = tid >> 6;
    const int lane = tid & 63;

    for (int i = tid; i < 4096; i += 256) gw_s[i >> 4][i & 15] = (double)g1w[i];
    for (int i = tid; i < 2048; i += 256) aw_s[i >> 3][i & 7]  = att_w[i];
    lsum[tid] = 0.0f;
    __syncthreads();

    const int bid = blockIdx.x;
    const int b   = bid / TILES;
    const int t0  = bid % TILES;
    const int wave_row0 = t0 * 256 + w * 64;
    const size_t bbase = (size_t)b * MM;

    const int kq   = lane & 1;     // which 16B half of the 32B k-chunk row
    const int rsub = lane >> 1;    // 0..31

    float  aacc[8];
    double gacc[16];
#pragma unroll
    for (int j = 0; j < 8; ++j) aacc[j] = 0.0f;
#pragma unroll
    for (int g = 0; g < 16; ++g) gacc[g] = 0.0;

    const int m0 = wave_row0 + rsub;
    const int m1 = wave_row0 + 32 + rsub;
    const size_t r0c = bbase + (size_t)((m0 < MM) ? m0 : (MM - 1));
    const size_t r1c = bbase + (size_t)((m1 < MM) ? m1 : (MM - 1));

    // stage chunk 0 (per-wave private tile; same-wave DS ops are in-order,
    // so no barrier needed between our writes and our reads)
    {
        float4 v0 = *(const float4*)(h + r0c * 256 + kq * 4);
        float4 v1 = *(const float4*)(h + r1c * 256 + kq * 4);
        if (m0 >= MM) { v0.x = v0.y = v0.z = v0.w = 0.f; }
        if (m1 >= MM) { v1.x = v1.y = v1.z = v1.w = 0.f; }
        tile[w][kq*4+0][rsub] = v0.x;  tile[w][kq*4+1][rsub] = v0.y;
        tile[w][kq*4+2][rsub] = v0.z;  tile[w][kq*4+3][rsub] = v0.w;
        tile[w][kq*4+0][32+rsub] = v1.x;  tile[w][kq*4+1][32+rsub] = v1.y;
        tile[w][kq*4+2][32+rsub] = v1.z;  tile[w][kq*4+3][32+rsub] = v1.w;
    }

    for (int c = 0; c < NCHUNK; ++c) {
        float4 n0, n1;
        const bool has = (c + 1 < NCHUNK);
        if (has) {
            const int kof = (c + 1) * CH + kq * 4;
            n0 = *(const float4*)(h + r0c * 256 + kof);
            n1 = *(const float4*)(h + r1c * 256 + kof);
            if (m0 >= MM) { n0.x = n0.y = n0.z = n0.w = 0.f; }
            if (m1 >= MM) { n1.x = n1.y = n1.z = n1.w = 0.f; }
        }
        const int k0 = c * CH;
#pragma unroll
        for (int kk = 0; kk < CH; ++kk) {
            float  hv = tile[w][kk][lane];
            double hd = (double)hv;
            const int kx = k0 + kk;
#pragma unroll
            for (int j = 0; j < 8; ++j) aacc[j] = fmaf(hv, aw_s[kx][j], aacc[j]);
#pragma unroll
            for (int g = 0; g < 16; ++g) gacc[g] = fma(hd, gw_s[kx][g], gacc[g]);
        }
        // column sums of this chunk (rides the staged tile)
        {
            const int dsub = lane & 7;
            const int rq   = lane >> 3;
            float s = 0.f;
#pragma unroll
            for (int i = 0; i < 8; ++i) s += tile[w][dsub][rq * 8 + i];
            s += __shfl_xor(s, 8, 64);
            s += __shfl_xor(s, 16, 64);
            s += __shfl_xor(s, 32, 64);
            if (lane < 8) atomicAdd(&lsum[k0 + lane], s);
        }
        if (has) {   // overwrite tile AFTER all reads of chunk c (in-order DS)
            tile[w][kq*4+0][rsub] = n0.x;  tile[w][kq*4+1][rsub] = n0.y;
            tile[w][kq*4+2][rsub] = n0.z;  tile[w][kq*4+3][rsub] = n0.w;
            tile[w][kq*4+0][32+rsub] = n1.x;  tile[w][kq*4+1][32+rsub] = n1.y;
            tile[w][kq*4+2][32+rsub] = n1.z;  tile[w][kq*4+3][32+rsub] = n1.w;
        }
    }

    // epilogue
    const int m = wave_row0 + lane;
    if (m < MM) {
        size_t row = bbase + (size_t)m;
        float4 A0, A1;
        A0.x = fmaxf(aacc[0] + att_b[0], 0.f);
        A0.y = fmaxf(aacc[1] + att_b[1], 0.f);
        A0.z = fmaxf(aacc[2] + att_b[2], 0.f);
        A0.w = fmaxf(aacc[3] + att_b[3], 0.f);
        A1.x = fmaxf(aacc[4] + att_b[4], 0.f);
        A1.y = fmaxf(aacc[5] + att_b[5], 0.f);
        A1.z = fmaxf(aacc[6] + att_b[6], 0.f);
        A1.w = fmaxf(aacc[7] + att_b[7], 0.f);
        float4* Ap = (float4*)(Aout + row * 8);
        Ap[0] = A0; Ap[1] = A1;

        double z = (double)g2b[0];
#pragma unroll
        for (int g = 0; g < 16; ++g) {
            double sg = gacc[g] + (double)g1b[g];
            sg = sg > 0.0 ? sg : 0.0;
            z = fma(sg, (double)g2w[g], z);
        }
        long long uz = __double_as_longlong(z);
        unsigned long long key = (uz < 0)
            ? ~((unsigned long long)uz)
            : ((unsigned long long)uz | 0x8000000000000000ULL);
        keys[row] = key;
    }
    __syncthreads();
    atomicAdd(&sumh[b * 256 + tid], (double)lsum[tid]);
}

// ---------------------------------------------------------------------------
// k2: exact kth-largest u64 key per batch WITHOUT wide histograms.
// 1024-sample bitonic sort -> pivot; exact count >= pivot (ballot/shfl
// aggregated); gather candidates to LDS; exact 64-bit bitwise select.
__global__ __launch_bounds__(1024) void k2_select(
    const unsigned long long* __restrict__ keys,
    const int* __restrict__ kptr,
    unsigned long long* __restrict__ kth)
{
    __shared__ unsigned long long buf[4096];
    __shared__ int s_cnt;
    __shared__ unsigned long long s_pivot;

    const int b    = blockIdx.x;
    const int tid  = threadIdx.x;
    const int lane = tid & 63;
    const size_t base = (size_t)b * MM;
    const int kval = min(*kptr, MM);

    buf[tid] = keys[base + (size_t)tid * 48];
    __syncthreads();
    // bitonic sort ascending, 1024 elements
    for (int sz = 2; sz <= 1024; sz <<= 1)
        for (int j = sz >> 1; j > 0; j >>= 1) {
            __syncthreads();
            int i = tid, ixj = i ^ j;
            if (ixj > i) {
                unsigned long long a = buf[i], c = buf[ixj];
                bool up = ((i & sz) == 0);
                if ((up && a > c) || (!up && a < c)) { buf[i] = c; buf[ixj] = a; }
            }
        }
    __syncthreads();

    // pivot loop: want kval <= n_ge <= 4096
    int R = 40;                       // descending sample rank (~true rank 2000)
    unsigned long long pivot = 0;
    for (int iter = 0; iter < 24; ++iter) {
        if (tid == 0) { s_pivot = buf[1023 - R]; s_cnt = 0; }
        __syncthreads();
        pivot = s_pivot;
        int loc = 0;
        for (int m = tid; m < MM; m += 1024)
            loc += (keys[base + m] >= pivot) ? 1 : 0;
        loc += __shfl_xor(loc, 32, 64);
        loc += __shfl_xor(loc, 16, 64);
        loc += __shfl_xor(loc, 8, 64);
        loc += __shfl_xor(loc, 4, 64);
        loc += __shfl_xor(loc, 2, 64);
        loc += __shfl_xor(loc, 1, 64);
        if (lane == 0) atomicAdd(&s_cnt, loc);
        __syncthreads();
        int n_ge = s_cnt;
        if (n_ge >= kval && n_ge <= 4096) break;
        R = (n_ge < kval) ? min(R + 48, 1023) : max(R - 16, 0);
        __syncthreads();
    }

    // gather candidate keys (>= pivot) into LDS, ballot-aggregated
    if (tid == 0) s_cnt = 0;
    __syncthreads();
    for (int m = tid; m < MM; m += 1024) {
        unsigned long long x = keys[base + m];
        bool p = (x >= pivot);
        unsigned long long ball = __ballot(p);
        int wbase = 0;
        if (lane == 0) { int wc = __popcll(ball); if (wc) wbase = atomicAdd(&s_cnt, wc); }
        wbase = __shfl(wbase, 0, 64);
        if (p) {
            int pos = wbase + __popcll(ball & ((1ull << lane) - 1ull));
            if (pos < 4096) buf[pos] = x;
        }
    }
    __syncthreads();
    const int n = min(s_cnt, 4096);

    // exact 64-bit bitwise select: kth largest among buf[0..n)
    unsigned long long p64 = 0;
    int kk = kval;
    for (int bit = 63; bit >= 0; --bit) {
        if (tid == 0) s_cnt = 0;
        __syncthreads();
        unsigned long long himask = (bit == 63) ? 0ull : (~0ull << (bit + 1));
        int loc = 0;
        for (int i = tid; i < n; i += 1024) {
            unsigned long long x = buf[i];
            if (((x ^ p64) & himask) == 0ull && ((x >> bit) & 1ull)) loc++;
        }
        loc += __shfl_xor(loc, 32, 64);
        loc += __shfl_xor(loc, 16, 64);
        loc += __shfl_xor(loc, 8, 64);
        loc += __shfl_xor(loc, 4, 64);
        loc += __shfl_xor(loc, 2, 64);
        loc += __shfl_xor(loc, 1, 64);
        if (lane == 0 && loc) atomicAdd(&s_cnt, loc);
        __syncthreads();
        int c1 = s_cnt;
        if (c1 >= kk) p64 |= (1ull << bit); else kk -= c1;
        __syncthreads();
    }
    if (tid == 0) kth[b] = p64;
}

// ---------------------------------------------------------------------------
// k3: mask output + ballot-aggregated compaction of masked indices
__global__ __launch_bounds__(256) void k3_mask(
    const unsigned long long* __restrict__ keys,
    const unsigned long long* __restrict__ kth,
    float* __restrict__ maskout,
    int* __restrict__ ccnt,
    int* __restrict__ compact)
{
    int bid = blockIdx.x;
    int b = bid / TILES, t0 = bid % TILES;
    int m = t0 * 256 + threadIdx.x;
    int lane = threadIdx.x & 63;
    bool mk = false;
    if (m < MM) {
        size_t row = (size_t)b * MM + m;
        mk = (keys[row] >= kth[b]);
        maskout[row] = mk ? 1.0f : 0.0f;
    }
    unsigned long long ball = __ballot(mk);
    int wbase = 0;
    if (lane == 0) { int wc = __popcll(ball); if (wc) wbase = atomicAdd(&ccnt[b], wc); }
    wbase = __shfl(wbase, 0, 64);
    if (mk) {
        int pos = wbase + __popcll(ball & ((1ull << lane) - 1ull));
        if (pos < 2048) compact[b * 2048 + pos] = m;
    }
}

// ---------------------------------------------------------------------------
// k4: sparse correction U_corr[b][h][d] = sum_{masked} (exp(A)-1)*h  (+Zcorr)
__global__ __launch_bounds__(256) void k4_corr(
    const float* __restrict__ h,
    const float* __restrict__ A,
    const int* __restrict__ compact,
    const int* __restrict__ ccnt,
    double* __restrict__ Ucorr,
    double* __restrict__ Zcorr)
{
    int b    = blockIdx.x >> 5;
    int part = blockIdx.x & 31;
    int tid  = threadIdx.x;
    int n = min(ccnt[b], 2048);
    float acc[8], zac[8];
#pragma unroll
    for (int j = 0; j < 8; ++j) { acc[j] = 0.f; zac[j] = 0.f; }
    for (int i = part; i < n; i += 32) {
        int m = compact[b * 2048 + i];
        size_t row = (size_t)b * MM + m;
        const float* Ap = A + row * 8;         // uniform per iter -> s_load
        float hv = h[row * 256 + tid];
#pragma unroll
        for (int j = 0; j < 8; ++j) {
            float ex = expf(Ap[j]) - 1.0f;
            acc[j] = fmaf(ex, hv, acc[j]);
            zac[j] += ex;
        }
    }
#pragma unroll
    for (int j = 0; j < 8; ++j)
        atomicAdd(&Ucorr[(b * 8 + j) * 256 + tid], (double)acc[j]);
    if (tid == 0) {
#pragma unroll
        for (int j = 0; j < 8; ++j) atomicAdd(&Zcorr[b * 8 + j], (double)zac[j]);
    }
}

// ---------------------------------------------------------------------------
// k5: epilogue. attn projection, Q_res, relu, normalize.
__global__ __launch_bounds__(256) void k5_final(
    const double* __restrict__ sumh,
    const double* __restrict__ Ucorr,
    const double* __restrict__ Zcorr,
    const int* __restrict__ ccnt,
    const float* __restrict__ w_w,     // [256][256]
    const float* __restrict__ res_w,   // [256][256]
    const float* __restrict__ res_b,   // [256]
    float* __restrict__ out0)
{
    __shared__ float Us[8 * 256];
    __shared__ float ms[256];
    __shared__ float red[256];
    __shared__ float s_mean, s_var;

    int b = blockIdx.x, e = threadIdx.x;
    double sh = sumh[b * 256 + e];
    ms[e] = (float)sh;
#pragma unroll
    for (int j = 0; j < 8; ++j)
        Us[j * 256 + e] = (float)(sh + Ucorr[(b * 8 + j) * 256 + e]);
    __syncthreads();

    int hh = e >> 5;
    float Z = (float)((double)(MM - ccnt[b]) + Zcorr[b * 8 + hh]);
    float attn = 0.f, qr = 0.f;
    for (int d = 0; d < 256; ++d) {
        attn = fmaf(Us[hh * 256 + d], w_w[d * 256 + e], attn);
        qr   = fmaf(ms[d],            res_w[d * 256 + e], qr);
    }
    float qres = fmaxf(qr * (1.0f / (float)MM) + res_b[e], 0.f);
    float pre  = fmaxf(attn / Z + qres, 0.f);

    red[e] = pre; __syncthreads();
    for (int s = 128; s > 0; s >>= 1) { if (e < s) red[e] += red[e + s]; __syncthreads(); }
    if (e == 0) s_mean = red[0] * (1.0f / 256.0f);
    __syncthreads();
    float mean = s_mean;
    float dv = pre - mean;
    red[e] = dv * dv; __syncthreads();
    for (int s = 128; s > 0; s >>= 1) { if (e < s) red[e] += red[e + s]; __syncthreads(); }
    if (e == 0) s_var = red[0] * (1.0f / 256.0f);
    __syncthreads();
    out0[b * 256 + e] = dv / sqrtf(s_var + 1e-8f);
}

// ---------------------------------------------------------------------------
extern "C" void kernel_launch(void* const* d_in, const int* in_sizes, int n_in,
                              void* d_out, int out_size, void* d_ws, size_t ws_size,
                              hipStream_t stream) {
    const float* h     = (const float*)d_in[0];
    const float* att_w = (const float*)d_in[1];
    const float* att_b = (const float*)d_in[2];
    const float* w_w   = (const float*)d_in[3];
    const float* res_w = (const float*)d_in[4];
    const float* res_b = (const float*)d_in[5];
    const float* g1w   = (const float*)d_in[6];
    const float* g1b   = (const float*)d_in[7];
    const float* g2w   = (const float*)d_in[8];
    const float* g2b   = (const float*)d_in[9];
    const int*   kptr  = (const int*)d_in[10];

    char* ws = (char*)d_ws;
    float*              A       = (float*)(ws + OFF_A);
    unsigned long long* keys    = (unsigned long long*)(ws + OFF_KEYS);
    double*             sumh    = (double*)(ws + OFF_SUMH);
    double*             Ucorr   = (double*)(ws + OFF_UCORR);
    double*             Zcorr   = (double*)(ws + OFF_ZCORR);
    int*                ccnt    = (int*)(ws + OFF_CCNT);
    unsigned long long* kth     = (unsigned long long*)(ws + OFF_KTH);
    int*                compact = (int*)(ws + OFF_COMPACT);

    float* out0    = (float*)d_out;
    float* maskout = out0 + BATCH * 256;   // output 1 after 8*1*256

    hipMemsetAsync(ws + OFF_SUMH, 0, ZERO_SZ, stream);

    k1_main  <<<BATCH*TILES, 256,  0, stream>>>(h, att_w, att_b, g1w, g1b, g2w, g2b,
                                                A, keys, sumh);
    k2_select<<<BATCH,       1024, 0, stream>>>(keys, kptr, kth);
    k3_mask  <<<BATCH*TILES, 256,  0, stream>>>(keys, kth, maskout, ccnt, compact);
    k4_corr  <<<BATCH*32,    256,  0, stream>>>(h, A, compact, ccnt, Ucorr, Zcorr);
    k5_final <<<BATCH,       256,  0, stream>>>(sumh, Ucorr, Zcorr, ccnt,
                                                w_w, res_w, res_b, out0);
}

// Round 3
// 830.117 us; speedup vs baseline: 1.2157x; 1.1289x over previous
//
#include <hip/hip_runtime.h>
#include <cstdint>
#include <cstddef>

// ---------------------------------------------------------------------------
// GATAttention: B=8, M=50000, d=256, heads=8, head_dim=32, gsl_hidden=16, k=500
//
//   U[b,h,:]  = sumh[b,:] + sum_{masked m} (exp(A[b,m,h])-1) * h[b,m,:]
//   Z[b,h]    = (M - cnt) + sum_{masked} exp(A[b,m,h])
//   out[b,e]  = normalize(relu( U[b,e>>5,:]@w_w[:,e]/Z + relu(mean_h@res_w+res_b) ))
//
// Round-3: k1 streams h computing ONLY the fp32 gate logit + column sums
// (no f64, no A). Top-k exactness via band + sparse f64 refinement:
//   k2  : sampled order-stat -> band cutoff 'lo' (~rank 2200, >=5 sigma margin)
//   k3  : rows below lo -> mask=0; band rows -> candidate list
//   k3r : exact f64 gate recompute for candidates only (~2200/batch)
//   k3s : exact 64-bit bitwise select of kth key among candidates,
//         write band masks, build masked-row compact list
//   k4  : recompute A for masked rows, accumulate Ucorr/Zcorr (f64)
//   k5  : epilogue
// ---------------------------------------------------------------------------

#define MM     50000
#define BATCH  8
#define TILES  196            // ceil(50000/256)
#define CH     8
#define NCHUNK 32             // 256/CH
#define CANDCAP 4096
#define COMPCAP 2048

// workspace layout (bytes)
#define OFF_Z      0u                 // float [B*M]        1,600,000
#define OFF_CANDR  1600000u           // int   [B*4096]       131,072
#define OFF_CANDK  1731072u           // u64   [B*4096]       262,144
#define OFF_COMP   1993216u           // int   [B*2048]        65,536
#define OFF_LO     2058752u           // u32   [8]                 32
#define OFF_PAD    2058784u           //                           64
// zeroed block:
#define OFF_SUMH   2058848u           // double [8*256]        16,384
#define OFF_UCORR  2075232u           // double [8*8*256]     131,072
#define OFF_ZCORR  2206304u           // double [8*8]             512
#define OFF_CCNT   2206816u           // int [8]                   32
#define OFF_CANDC  2206848u           // int [8]                   32
#define ZERO_OFF   OFF_SUMH
#define ZERO_SZ    148032u

__device__ __forceinline__ unsigned int f32_sortable(float z) {
    unsigned int u = __float_as_uint(z);
    return (u & 0x80000000u) ? ~u : (u | 0x80000000u);
}

// ---------------------------------------------------------------------------
// k1: stream h. fp32 gate logit + column sums only. Weights via s_load.
__global__ __launch_bounds__(256) void k1_main(
    const float* __restrict__ h,
    const float* __restrict__ g1w,     // [256][16]
    const float* __restrict__ g1b,     // [16]
    const float* __restrict__ g2w,     // [16]
    const float* __restrict__ g2b,     // [1]
    float* __restrict__ z32,           // [B*M]
    double* __restrict__ sumh)         // [B][256]
{
    __shared__ float tile[4][CH][65];     // [wave][k][row+pad]  ~8.3 KB
    __shared__ float lsum[256];

    const int tid  = threadIdx.x;
    const int w    = tid >> 6;
    const int lane = tid & 63;
    lsum[tid] = 0.0f;
    __syncthreads();

    const int bid = blockIdx.x;
    const int b   = bid / TILES;
    const int t0  = bid % TILES;
    const int wave_row0 = t0 * 256 + w * 64;
    const size_t bbase = (size_t)b * MM;

    const int kq   = lane & 1;
    const int rsub = lane >> 1;

    float gacc[16];
#pragma unroll
    for (int g = 0; g < 16; ++g) gacc[g] = 0.0f;

    const int m0 = wave_row0 + rsub;
    const int m1 = wave_row0 + 32 + rsub;
    const size_t r0c = bbase + (size_t)((m0 < MM) ? m0 : (MM - 1));
    const size_t r1c = bbase + (size_t)((m1 < MM) ? m1 : (MM - 1));

    // stage chunk 0 (wave-private tile, same-wave DS is in-order)
    {
        float4 v0 = *(const float4*)(h + r0c * 256 + kq * 4);
        float4 v1 = *(const float4*)(h + r1c * 256 + kq * 4);
        if (m0 >= MM) { v0.x = v0.y = v0.z = v0.w = 0.f; }
        if (m1 >= MM) { v1.x = v1.y = v1.z = v1.w = 0.f; }
        tile[w][kq*4+0][rsub] = v0.x;  tile[w][kq*4+1][rsub] = v0.y;
        tile[w][kq*4+2][rsub] = v0.z;  tile[w][kq*4+3][rsub] = v0.w;
        tile[w][kq*4+0][32+rsub] = v1.x;  tile[w][kq*4+1][32+rsub] = v1.y;
        tile[w][kq*4+2][32+rsub] = v1.z;  tile[w][kq*4+3][32+rsub] = v1.w;
    }

    for (int c = 0; c < NCHUNK; ++c) {
        float4 n0, n1;
        const bool has = (c + 1 < NCHUNK);
        if (has) {
            const int kof = (c + 1) * CH + kq * 4;
            n0 = *(const float4*)(h + r0c * 256 + kof);
            n1 = *(const float4*)(h + r1c * 256 + kof);
            if (m0 >= MM) { n0.x = n0.y = n0.z = n0.w = 0.f; }
            if (m1 >= MM) { n1.x = n1.y = n1.z = n1.w = 0.f; }
        }
        const int k0 = c * CH;
#pragma unroll
        for (int kk = 0; kk < CH; ++kk) {
            float hv = tile[w][kk][lane];
            const float* gw = g1w + (k0 + kk) * 16;   // wave-uniform -> s_load
#pragma unroll
            for (int g = 0; g < 16; ++g) gacc[g] = fmaf(hv, gw[g], gacc[g]);
        }
        // column sums ride the staged tile
        {
            const int dsub = lane & 7;
            const int rq   = lane >> 3;
            float s = 0.f;
#pragma unroll
            for (int i = 0; i < 8; ++i) s += tile[w][dsub][rq * 8 + i];
            s += __shfl_xor(s, 8, 64);
            s += __shfl_xor(s, 16, 64);
            s += __shfl_xor(s, 32, 64);
            if (lane < 8) atomicAdd(&lsum[k0 + lane], s);
        }
        if (has) {   // overwrite AFTER all reads of chunk c (in-order DS)
            tile[w][kq*4+0][rsub] = n0.x;  tile[w][kq*4+1][rsub] = n0.y;
            tile[w][kq*4+2][rsub] = n0.z;  tile[w][kq*4+3][rsub] = n0.w;
            tile[w][kq*4+0][32+rsub] = n1.x;  tile[w][kq*4+1][32+rsub] = n1.y;
            tile[w][kq*4+2][32+rsub] = n1.z;  tile[w][kq*4+3][32+rsub] = n1.w;
        }
    }

    const int m = wave_row0 + lane;
    if (m < MM) {
        float z = g2b[0];
#pragma unroll
        for (int g = 0; g < 16; ++g) {
            float sg = gacc[g] + g1b[g];
            sg = fmaxf(sg, 0.0f);
            z = fmaf(sg, g2w[g], z);
        }
        z32[bbase + m] = z;
    }
    __syncthreads();
    atomicAdd(&sumh[b * 256 + tid], (double)lsum[tid]);
}

// ---------------------------------------------------------------------------
// k2: sampled order statistic -> band cutoff lo (sortable u32)
__global__ __launch_bounds__(1024) void k2_sample(
    const float* __restrict__ z32,
    const int* __restrict__ kptr,
    unsigned int* __restrict__ lo_out)
{
    __shared__ unsigned int buf[1024];
    const int b   = blockIdx.x;
    const int tid = threadIdx.x;
    const size_t base = (size_t)b * MM;
    const int kval = min(*kptr, MM);

    int idx = (int)(((long long)tid * MM) / 1024);
    buf[tid] = f32_sortable(z32[base + idx]);
    __syncthreads();
    for (int sz = 2; sz <= 1024; sz <<= 1)
        for (int j = sz >> 1; j > 0; j >>= 1) {
            __syncthreads();
            int i = tid, ixj = i ^ j;
            if (ixj > i) {
                unsigned int a = buf[i], c = buf[ixj];
                bool up = ((i & sz) == 0);
                if ((up && a > c) || (!up && a < c)) { buf[i] = c; buf[ixj] = a; }
            }
        }
    __syncthreads();
    if (tid == 0) {
        int ks = (int)(((long long)kval * 1024) / MM) + 35;  // ~rank k+1700
        ks = min(1023, max(1, ks));
        lo_out[b] = buf[1023 - ks];
    }
}

// ---------------------------------------------------------------------------
// k3: rows below band -> mask=0; band rows -> candidate list (ballot append)
__global__ __launch_bounds__(256) void k3_band(
    const float* __restrict__ z32,
    const unsigned int* __restrict__ lo_in,
    float* __restrict__ maskout,
    int* __restrict__ cand_cnt,
    int* __restrict__ cand_rows)
{
    int bid = blockIdx.x;
    int b = bid / TILES, t0 = bid % TILES;
    int m = t0 * 256 + threadIdx.x;
    int lane = threadIdx.x & 63;
    bool cand = false;
    if (m < MM) {
        size_t row = (size_t)b * MM + m;
        cand = (f32_sortable(z32[row]) >= lo_in[b]);
        if (!cand) maskout[row] = 0.0f;     // band rows written in k3s
    }
    unsigned long long ball = __ballot(cand);
    int wbase = 0;
    if (lane == 0) { int wc = __popcll(ball); if (wc) wbase = atomicAdd(&cand_cnt[b], wc); }
    wbase = __shfl(wbase, 0, 64);
    if (cand) {
        int pos = wbase + __popcll(ball & ((1ull << lane) - 1ull));
        if (pos < CANDCAP) cand_rows[b * CANDCAP + pos] = m;
    }
}

// ---------------------------------------------------------------------------
// k3r: exact f64 gate recompute for candidates (one thread per candidate)
__global__ __launch_bounds__(256) void k3r_refine(
    const float* __restrict__ h,
    const float* __restrict__ g1w,
    const float* __restrict__ g1b,
    const float* __restrict__ g2w,
    const float* __restrict__ g2b,
    const int* __restrict__ cand_cnt,
    const int* __restrict__ cand_rows,
    unsigned long long* __restrict__ cand_keys)
{
    __shared__ double g1s[256][16];   // 32 KB
    const int b    = blockIdx.x >> 4;
    const int part = blockIdx.x & 15;
    const int tid  = threadIdx.x;
    for (int i = tid; i < 4096; i += 256) g1s[i >> 4][i & 15] = (double)g1w[i];
    __syncthreads();

    const int n = min(cand_cnt[b], CANDCAP);
    const size_t bbase = (size_t)b * MM;
    for (int slot = part * 256 + tid; slot < n; slot += 4096) {
        int row = cand_rows[b * CANDCAP + slot];
        const float* hp = h + (bbase + (size_t)row) * 256;
        double gacc[16];
#pragma unroll
        for (int g = 0; g < 16; ++g) gacc[g] = 0.0;
        for (int k = 0; k < 256; ++k) {
            double hd = (double)hp[k];
#pragma unroll
            for (int g = 0; g < 16; ++g) gacc[g] = fma(hd, g1s[k][g], gacc[g]);
        }
        double z = (double)g2b[0];
#pragma unroll
        for (int g = 0; g < 16; ++g) {
            double sg = gacc[g] + (double)g1b[g];
            sg = sg > 0.0 ? sg : 0.0;
            z = fma(sg, (double)g2w[g], z);
        }
        long long uz = __double_as_longlong(z);
        unsigned long long key = (uz < 0)
            ? ~((unsigned long long)uz)
            : ((unsigned long long)uz | 0x8000000000000000ULL);
        cand_keys[b * CANDCAP + slot] = key;
    }
}

// ---------------------------------------------------------------------------
// k3s: exact kth-largest among candidate f64 keys; write band masks; build
// masked-row compact list.
__global__ __launch_bounds__(1024) void k3s_select(
    const int* __restrict__ kptr,
    const int* __restrict__ cand_cnt,
    const int* __restrict__ cand_rows,
    const unsigned long long* __restrict__ cand_keys,
    float* __restrict__ maskout,
    int* __restrict__ ccnt,
    int* __restrict__ compact)
{
    __shared__ unsigned long long kbuf[CANDCAP];   // 32 KB
    __shared__ int s_cnt;

    const int b    = blockIdx.x;
    const int tid  = threadIdx.x;
    const int lane = tid & 63;
    const int n = min(cand_cnt[b], CANDCAP);
    const size_t bbase = (size_t)b * MM;
    int kval = min(*kptr, MM);
    if (kval > n) kval = n;   // safety (analysis: n ~ 2200 >> k)

    for (int i = tid; i < n; i += 1024) kbuf[i] = cand_keys[b * CANDCAP + i];
    __syncthreads();

    unsigned long long p64 = 0;
    int kk = kval;
    for (int bit = 63; bit >= 0; --bit) {
        if (tid == 0) s_cnt = 0;
        __syncthreads();
        unsigned long long himask = (bit == 63) ? 0ull : (~0ull << (bit + 1));
        int loc = 0;
        for (int i = tid; i < n; i += 1024) {
            unsigned long long x = kbuf[i];
            if (((x ^ p64) & himask) == 0ull && ((x >> bit) & 1ull)) loc++;
        }
        loc += __shfl_xor(loc, 32, 64);
        loc += __shfl_xor(loc, 16, 64);
        loc += __shfl_xor(loc, 8, 64);
        loc += __shfl_xor(loc, 4, 64);
        loc += __shfl_xor(loc, 2, 64);
        loc += __shfl_xor(loc, 1, 64);
        if (lane == 0 && loc) atomicAdd(&s_cnt, loc);
        __syncthreads();
        int c1 = s_cnt;
        if (c1 >= kk) p64 |= (1ull << bit); else kk -= c1;
        __syncthreads();
    }

    // masks + compact list for in-mask rows
    for (int i0 = 0; i0 < n; i0 += 1024) {
        int i = i0 + tid;
        bool active = (i < n);
        bool mk = false;
        int row = 0;
        if (active) {
            row = cand_rows[b * CANDCAP + i];
            mk = (kbuf[i] >= p64);
            maskout[bbase + row] = mk ? 1.0f : 0.0f;
        }
        unsigned long long ball = __ballot(mk);
        int wbase = 0;
        if (lane == 0) { int wc = __popcll(ball); if (wc) wbase = atomicAdd(&ccnt[b], wc); }
        wbase = __shfl(wbase, 0, 64);
        if (mk) {
            int pos = wbase + __popcll(ball & ((1ull << lane) - 1ull));
            if (pos < COMPCAP) compact[b * COMPCAP + pos] = row;
        }
    }
}

// ---------------------------------------------------------------------------
// k4: recompute A for masked rows; Ucorr[b][h][d] += (exp(A)-1)*h; Zcorr.
__global__ __launch_bounds__(256) void k4_corr(
    const float* __restrict__ h,
    const float* __restrict__ att_w,   // [256][8]
    const float* __restrict__ att_b,   // [8]
    const int* __restrict__ compact,
    const int* __restrict__ ccnt,
    double* __restrict__ Ucorr,
    double* __restrict__ Zcorr)
{
    __shared__ float hv_s[256];
    __shared__ float a_s[8];

    const int b    = blockIdx.x >> 5;
    const int part = blockIdx.x & 31;
    const int tid  = threadIdx.x;
    const int head = tid >> 5;
    const int seg  = tid & 31;
    const size_t bbase = (size_t)b * MM;
    const int n = min(ccnt[b], COMPCAP);

    float acc[8], zac[8];
#pragma unroll
    for (int j = 0; j < 8; ++j) { acc[j] = 0.f; zac[j] = 0.f; }

    for (int i = part; i < n; i += 32) {
        int row = compact[b * COMPCAP + i];
        float hv = h[(bbase + (size_t)row) * 256 + tid];
        hv_s[tid] = hv;
        __syncthreads();
        float p = 0.f;
#pragma unroll
        for (int j = 0; j < 8; ++j)
            p = fmaf(hv_s[seg * 8 + j], att_w[(seg * 8 + j) * 8 + head], p);
        p += __shfl_xor(p, 1, 64);
        p += __shfl_xor(p, 2, 64);
        p += __shfl_xor(p, 4, 64);
        p += __shfl_xor(p, 8, 64);
        p += __shfl_xor(p, 16, 64);
        if (seg == 0) a_s[head] = fmaxf(p + att_b[head], 0.f);
        __syncthreads();
#pragma unroll
        for (int j = 0; j < 8; ++j) {
            float w8 = expf(a_s[j]) - 1.0f;
            acc[j] = fmaf(w8, hv, acc[j]);
            zac[j] += w8;
        }
        __syncthreads();
    }
#pragma unroll
    for (int j = 0; j < 8; ++j)
        atomicAdd(&Ucorr[(b * 8 + j) * 256 + tid], (double)acc[j]);
    if (tid == 0) {
#pragma unroll
        for (int j = 0; j < 8; ++j) atomicAdd(&Zcorr[b * 8 + j], (double)zac[j]);
    }
}

// ---------------------------------------------------------------------------
// k5: epilogue
__global__ __launch_bounds__(256) void k5_final(
    const double* __restrict__ sumh,
    const double* __restrict__ Ucorr,
    const double* __restrict__ Zcorr,
    const int* __restrict__ ccnt,
    const float* __restrict__ w_w,     // [256][256]
    const float* __restrict__ res_w,   // [256][256]
    const float* __restrict__ res_b,   // [256]
    float* __restrict__ out0)
{
    __shared__ float Us[8 * 256];
    __shared__ float ms[256];
    __shared__ float red[256];
    __shared__ float s_mean, s_var;

    int b = blockIdx.x, e = threadIdx.x;
    double sh = sumh[b * 256 + e];
    ms[e] = (float)sh;
#pragma unroll
    for (int j = 0; j < 8; ++j)
        Us[j * 256 + e] = (float)(sh + Ucorr[(b * 8 + j) * 256 + e]);
    __syncthreads();

    int hh = e >> 5;
    float Z = (float)((double)(MM - ccnt[b]) + Zcorr[b * 8 + hh]);
    float attn = 0.f, qr = 0.f;
    for (int d = 0; d < 256; ++d) {
        attn = fmaf(Us[hh * 256 + d], w_w[d * 256 + e], attn);
        qr   = fmaf(ms[d],            res_w[d * 256 + e], qr);
    }
    float qres = fmaxf(qr * (1.0f / (float)MM) + res_b[e], 0.f);
    float pre  = fmaxf(attn / Z + qres, 0.f);

    red[e] = pre; __syncthreads();
    for (int s = 128; s > 0; s >>= 1) { if (e < s) red[e] += red[e + s]; __syncthreads(); }
    if (e == 0) s_mean = red[0] * (1.0f / 256.0f);
    __syncthreads();
    float mean = s_mean;
    float dv = pre - mean;
    red[e] = dv * dv; __syncthreads();
    for (int s = 128; s > 0; s >>= 1) { if (e < s) red[e] += red[e + s]; __syncthreads(); }
    if (e == 0) s_var = red[0] * (1.0f / 256.0f);
    __syncthreads();
    out0[b * 256 + e] = dv / sqrtf(s_var + 1e-8f);
}

// ---------------------------------------------------------------------------
extern "C" void kernel_launch(void* const* d_in, const int* in_sizes, int n_in,
                              void* d_out, int out_size, void* d_ws, size_t ws_size,
                              hipStream_t stream) {
    const float* h     = (const float*)d_in[0];
    const float* att_w = (const float*)d_in[1];
    const float* att_b = (const float*)d_in[2];
    const float* w_w   = (const float*)d_in[3];
    const float* res_w = (const float*)d_in[4];
    const float* res_b = (const float*)d_in[5];
    const float* g1w   = (const float*)d_in[6];
    const float* g1b   = (const float*)d_in[7];
    const float* g2w   = (const float*)d_in[8];
    const float* g2b   = (const float*)d_in[9];
    const int*   kptr  = (const int*)d_in[10];

    char* ws = (char*)d_ws;
    float*              z32     = (float*)(ws + OFF_Z);
    int*                candr   = (int*)(ws + OFF_CANDR);
    unsigned long long* candk   = (unsigned long long*)(ws + OFF_CANDK);
    int*                compact = (int*)(ws + OFF_COMP);
    unsigned int*       lo      = (unsigned int*)(ws + OFF_LO);
    double*             sumh    = (double*)(ws + OFF_SUMH);
    double*             Ucorr   = (double*)(ws + OFF_UCORR);
    double*             Zcorr   = (double*)(ws + OFF_ZCORR);
    int*                ccnt    = (int*)(ws + OFF_CCNT);
    int*                candc   = (int*)(ws + OFF_CANDC);

    float* out0    = (float*)d_out;
    float* maskout = out0 + BATCH * 256;

    hipMemsetAsync(ws + ZERO_OFF, 0, ZERO_SZ, stream);

    k1_main   <<<BATCH*TILES, 256,  0, stream>>>(h, g1w, g1b, g2w, g2b, z32, sumh);
    k2_sample <<<BATCH,       1024, 0, stream>>>(z32, kptr, lo);
    k3_band   <<<BATCH*TILES, 256,  0, stream>>>(z32, lo, maskout, candc, candr);
    k3r_refine<<<BATCH*16,    256,  0, stream>>>(h, g1w, g1b, g2w, g2b,
                                                 candc, candr, candk);
    k3s_select<<<BATCH,       1024, 0, stream>>>(kptr, candc, candr, candk,
                                                 maskout, ccnt, compact);
    k4_corr   <<<BATCH*32,    256,  0, stream>>>(h, att_w, att_b, compact, ccnt,
                                                 Ucorr, Zcorr);
    k5_final  <<<BATCH,       256,  0, stream>>>(sumh, Ucorr, Zcorr, ccnt,
                                                 w_w, res_w, res_b, out0);
}